// Round 7
// baseline (53.395 us; speedup 1.0000x reference)
//
#include <hip/hip_runtime.h>

#define NS 128   // samples per ray
#define NF 32    // features

// Full per-ray pipeline (identical math to R4's validated path).
__device__ __forceinline__ void process_ray(
    const float* __restrict__ depths, const float* __restrict__ sigma,
    const float* __restrict__ feats, const int* __restrict__ valid,
    float* __restrict__ out_feats, float* __restrict__ out_depth,
    float* __restrict__ out_ws, float* __restrict__ out_alpha,
    int ray, int lane, int j, int q)
{
    if (valid[ray] == 0) {
        // outputs are exactly zero; no input bytes needed
        if (j == 0)
            ((float4*)(out_feats + (size_t)ray * NF))[q] = make_float4(0.f, 0.f, 0.f, 0.f);
        if (lane == 0) {
            out_depth[ray] = 0.f; out_ws[ray] = 0.f; out_alpha[ray] = 0.f;
        }
        return;
    }

    // ---------- issue scan inputs first (vmcnt retires in order) ----------
    const float* dp = depths + (size_t)ray * NS;
    const float* sp = sigma  + (size_t)ray * NS;
    float d_lo = dp[lane];
    float d_hi = dp[lane + 64];
    float s_lo = sp[lane];
    float s_hi = sp[lane + 64];

    // ---------- issue the feats stream: 16 x float4 / lane ----------
    const float4* fptr = (const float4*)(feats + (size_t)ray * NS * NF);
    float4 v0[8], v1[8];
    #pragma unroll
    for (int it = 0; it < 8; ++it)
        v0[it] = fptr[(it * 8 + j) * 8 + q];
    #pragma unroll
    for (int it = 0; it < 8; ++it)
        v1[it] = fptr[((it + 8) * 8 + j) * 8 + q];

    // ---------- phase 1: free energy + wave-wide inclusive scan ----------
    float d_lo_nb = __shfl(d_lo, (lane + 1) & 63, 64);
    float d_hi_nb = __shfl(d_hi, (lane + 1) & 63, 64);
    float d64     = __shfl(d_hi, 0, 64);
    float d_lo_n  = (lane == 63) ? d64  : d_lo_nb;
    float d_hi_n  = (lane == 63) ? d_hi : d_hi_nb;   // last dist = 0

    float fe_lo = (d_lo_n - d_lo) * s_lo;
    float fe_hi = (d_hi_n - d_hi) * s_hi;

    float c_lo = fe_lo;
    #pragma unroll
    for (int off = 1; off < 64; off <<= 1) {
        float t = __shfl_up(c_lo, off, 64);
        if (lane >= off) c_lo += t;
    }
    float tot_lo = __shfl(c_lo, 63, 64);
    float c_hi = fe_hi;
    #pragma unroll
    for (int off = 1; off < 64; off <<= 1) {
        float t = __shfl_up(c_hi, off, 64);
        if (lane >= off) c_hi += t;
    }
    c_hi += tot_lo;

    // w = alpha * exp(fe - cum) = exp(fe - cum) - exp(-cum)
    float w_lo = expf(fe_lo - c_lo) - expf(-c_lo);
    float w_hi = expf(fe_hi - c_hi) - expf(-c_hi);
    float a_lo = 1.0f - expf(-fe_lo);
    float a_hi = 1.0f - expf(-fe_hi);

    // scalar reductions: depth, alpha, weight-sum (overlap feats flight)
    float dsum = w_lo * d_lo + w_hi * d_hi;
    float asum = w_lo * a_lo + w_hi * a_hi;
    float wsum = w_lo + w_hi;
    #pragma unroll
    for (int m = 1; m < 64; m <<= 1) {
        dsum += __shfl_xor(dsum, m, 64);
        asum += __shfl_xor(asum, m, 64);
        wsum += __shfl_xor(wsum, m, 64);
    }
    if (lane == 0) {
        out_depth[ray] = dsum;
        out_ws[ray]    = wsum;
        out_alpha[ray] = asum;
    }

    // ---------- phase 2: feats contraction (weights via in-wave shuffle) ----------
    float4 acc = make_float4(0.f, 0.f, 0.f, 0.f);
    #pragma unroll
    for (int it = 0; it < 8; ++it) {
        const float w = __shfl(w_lo, it * 8 + j, 64);
        acc.x += w * v0[it].x;
        acc.y += w * v0[it].y;
        acc.z += w * v0[it].z;
        acc.w += w * v0[it].w;
    }
    #pragma unroll
    for (int it = 0; it < 8; ++it) {
        const float w = __shfl(w_hi, it * 8 + j, 64);
        acc.x += w * v1[it].x;
        acc.y += w * v1[it].y;
        acc.z += w * v1[it].z;
        acc.w += w * v1[it].w;
    }
    #pragma unroll
    for (int m = 8; m < 64; m <<= 1) {
        acc.x += __shfl_xor(acc.x, m, 64);
        acc.y += __shfl_xor(acc.y, m, 64);
        acc.z += __shfl_xor(acc.z, m, 64);
        acc.w += __shfl_xor(acc.w, m, 64);
    }
    if (j == 0)
        ((float4*)(out_feats + (size_t)ray * NF))[q] = acc;
}

// One kernel: static first ray per wave (rays [0, nwaves)), then dynamic
// tickets from 4 partitioned counters for rays [nwaves, n_rays). Dynamic
// assignment removes the per-CU Binomial(32,1/2) valid-count tail.
__global__ __launch_bounds__(256)
void volren_dyn(const float* __restrict__ depths,
                const float* __restrict__ sigma,
                const float* __restrict__ feats,
                const int*   __restrict__ valid,
                int* __restrict__ counters,          // 4 counters, 64B apart
                float* __restrict__ out_feats,
                float* __restrict__ out_depth,
                float* __restrict__ out_ws,
                float* __restrict__ out_alpha,
                int n_rays)
{
    const int lane  = threadIdx.x & 63;
    const int gwave = blockIdx.x * 4 + (threadIdx.x >> 6);
    const int j = lane >> 3;
    const int q = lane & 7;

    const int nwaves   = gridDim.x * 4;                 // 4096
    const int dyn_base = nwaves;
    const int part     = gwave & 3;
    const int part_sz  = (n_rays - dyn_base + 3) >> 2;  // 1024
    int* ctr = counters + part * 16;                    // separate cachelines

    // grab the first dynamic ticket early (in flight during the static ray)
    int t = 0;
    if (lane == 0) t = atomicAdd(ctr, 1);
    t = __shfl(t, 0, 64);

    // static ray
    if (gwave < n_rays)
        process_ray(depths, sigma, feats, valid, out_feats, out_depth,
                    out_ws, out_alpha, gwave, lane, j, q);

    // dynamic rays
    while (t < part_sz) {
        const int ray = dyn_base + part * part_sz + t;
        // grab the next ticket before processing (hides the atomic's latency)
        int nt = 0;
        if (lane == 0) nt = atomicAdd(ctr, 1);
        nt = __shfl(nt, 0, 64);
        if (ray < n_rays)
            process_ray(depths, sigma, feats, valid, out_feats, out_depth,
                        out_ws, out_alpha, ray, lane, j, q);
        t = nt;
    }
}

extern "C" void kernel_launch(void* const* d_in, const int* in_sizes, int n_in,
                              void* d_out, int out_size, void* d_ws, size_t ws_size,
                              hipStream_t stream) {
    const float* depths = (const float*)d_in[0];   // sampled_depths [B,R,S]
    const float* sigma  = (const float*)d_in[1];   // sigma          [B,R,S]
    const float* feats  = (const float*)d_in[2];   // feats          [B,R,S,F]
    // d_in[3] = max_depths (unused by the reference math)
    const int*   valid  = (const int*)d_in[4];     // valid_rays     [B,R]

    const int n_rays = in_sizes[4];                // B*R = 8192

    float* out       = (float*)d_out;
    float* out_feats = out;                               // [n_rays, NF]
    float* out_depth = out + (size_t)n_rays * NF;         // [n_rays]
    float* out_ws    = out_depth + n_rays;                // [n_rays]
    float* out_alpha = out_ws + n_rays;                   // [n_rays]

    int* counters = (int*)d_ws;                    // 4 counters, 64B apart
    hipMemsetAsync(counters, 0, 256, stream);      // single tiny graph node

    volren_dyn<<<1024, 256, 0, stream>>>(depths, sigma, feats, valid, counters,
                                         out_feats, out_depth, out_ws,
                                         out_alpha, n_rays);
}

// Round 8
// 17.347 us; speedup vs baseline: 3.0781x; 3.0781x over previous
//
#include <hip/hip_runtime.h>

#define NS 128   // samples per ray
#define NF 32    // features

// One wave per ray, 2048 blocks x 4 waves. __launch_bounds__(256,3) caps
// residency at 3 blocks/CU -> ~768 of 2048 blocks resident; the hardware
// dispatcher hands the remaining blocks to CUs as they drain, dynamically
// rebalancing the random valid/invalid work split (no atomics, no extra
// graph nodes). Invalid rays: inline zero-writes, no input traffic.
__global__ __launch_bounds__(256, 3)
void volren_kernel(const float* __restrict__ depths,   // [n_rays, NS]
                   const float* __restrict__ sigma,    // [n_rays, NS]
                   const float* __restrict__ feats,    // [n_rays, NS, NF]
                   const int*   __restrict__ valid,    // [n_rays]
                   float* __restrict__ out_feats,      // [n_rays, NF]
                   float* __restrict__ out_depth,      // [n_rays]
                   float* __restrict__ out_ws,         // [n_rays]
                   float* __restrict__ out_alpha,      // [n_rays]
                   int n_rays)
{
    const int lane = threadIdx.x & 63;
    const int ray  = blockIdx.x * 4 + (threadIdx.x >> 6);
    if (ray >= n_rays) return;

    const int j = lane >> 3;       // sample-sub index in [0,8)
    const int q = lane & 7;        // float4 quad index in [0,8)

    if (valid[ray] == 0) {
        // outputs are exactly zero; no input bytes needed
        if (j == 0)
            ((float4*)(out_feats + (size_t)ray * NF))[q] =
                make_float4(0.f, 0.f, 0.f, 0.f);
        if (lane == 0) {
            out_depth[ray] = 0.f;
            out_ws[ray]    = 0.f;
            out_alpha[ray] = 0.f;
        }
        return;
    }

    // ---------- issue scan inputs first (vmcnt retires in order) ----------
    const float* dp = depths + (size_t)ray * NS;
    const float* sp = sigma  + (size_t)ray * NS;
    float d_lo = dp[lane];
    float d_hi = dp[lane + 64];
    float s_lo = sp[lane];
    float s_hi = sp[lane + 64];

    // ---------- issue the feats stream: 16 x float4 / lane ----------
    const float4* fptr = (const float4*)(feats + (size_t)ray * NS * NF);
    float4 v0[8], v1[8];
    #pragma unroll
    for (int it = 0; it < 8; ++it)
        v0[it] = fptr[(it * 8 + j) * 8 + q];
    #pragma unroll
    for (int it = 0; it < 8; ++it)
        v1[it] = fptr[((it + 8) * 8 + j) * 8 + q];

    // ---------- phase 1: free energy + wave-wide inclusive scan ----------
    float d_lo_nb = __shfl(d_lo, (lane + 1) & 63, 64);
    float d_hi_nb = __shfl(d_hi, (lane + 1) & 63, 64);
    float d64     = __shfl(d_hi, 0, 64);
    float d_lo_n  = (lane == 63) ? d64  : d_lo_nb;
    float d_hi_n  = (lane == 63) ? d_hi : d_hi_nb;   // last dist = 0

    float fe_lo = (d_lo_n - d_lo) * s_lo;
    float fe_hi = (d_hi_n - d_hi) * s_hi;

    float c_lo = fe_lo;
    #pragma unroll
    for (int off = 1; off < 64; off <<= 1) {
        float t = __shfl_up(c_lo, off, 64);
        if (lane >= off) c_lo += t;
    }
    float tot_lo = __shfl(c_lo, 63, 64);
    float c_hi = fe_hi;
    #pragma unroll
    for (int off = 1; off < 64; off <<= 1) {
        float t = __shfl_up(c_hi, off, 64);
        if (lane >= off) c_hi += t;
    }
    c_hi += tot_lo;

    // w = alpha * exp(fe - cum) = exp(fe - cum) - exp(-cum)
    float w_lo = expf(fe_lo - c_lo) - expf(-c_lo);
    float w_hi = expf(fe_hi - c_hi) - expf(-c_hi);
    float a_lo = 1.0f - expf(-fe_lo);
    float a_hi = 1.0f - expf(-fe_hi);

    // scalar reductions: depth, alpha, weight-sum (overlap feats flight)
    float dsum = w_lo * d_lo + w_hi * d_hi;
    float asum = w_lo * a_lo + w_hi * a_hi;
    float wsum = w_lo + w_hi;
    #pragma unroll
    for (int m = 1; m < 64; m <<= 1) {
        dsum += __shfl_xor(dsum, m, 64);
        asum += __shfl_xor(asum, m, 64);
        wsum += __shfl_xor(wsum, m, 64);
    }
    if (lane == 0) {
        out_depth[ray] = dsum;
        out_ws[ray]    = wsum;
        out_alpha[ray] = asum;
    }

    // ---------- phase 2: feats contraction (weights via in-wave shuffle) ----------
    float4 acc = make_float4(0.f, 0.f, 0.f, 0.f);
    #pragma unroll
    for (int it = 0; it < 8; ++it) {
        const float w = __shfl(w_lo, it * 8 + j, 64);
        acc.x += w * v0[it].x;
        acc.y += w * v0[it].y;
        acc.z += w * v0[it].z;
        acc.w += w * v0[it].w;
    }
    #pragma unroll
    for (int it = 0; it < 8; ++it) {
        const float w = __shfl(w_hi, it * 8 + j, 64);
        acc.x += w * v1[it].x;
        acc.y += w * v1[it].y;
        acc.z += w * v1[it].z;
        acc.w += w * v1[it].w;
    }
    // reduce across the 8 sample-sub lanes (stride 8)
    #pragma unroll
    for (int m = 8; m < 64; m <<= 1) {
        acc.x += __shfl_xor(acc.x, m, 64);
        acc.y += __shfl_xor(acc.y, m, 64);
        acc.z += __shfl_xor(acc.z, m, 64);
        acc.w += __shfl_xor(acc.w, m, 64);
    }
    if (j == 0)
        ((float4*)(out_feats + (size_t)ray * NF))[q] = acc;
}

extern "C" void kernel_launch(void* const* d_in, const int* in_sizes, int n_in,
                              void* d_out, int out_size, void* d_ws, size_t ws_size,
                              hipStream_t stream) {
    const float* depths = (const float*)d_in[0];   // sampled_depths [B,R,S]
    const float* sigma  = (const float*)d_in[1];   // sigma          [B,R,S]
    const float* feats  = (const float*)d_in[2];   // feats          [B,R,S,F]
    // d_in[3] = max_depths (unused by the reference math)
    const int*   valid  = (const int*)d_in[4];     // valid_rays     [B,R]

    const int n_rays = in_sizes[4];                // B*R = 8192

    float* out       = (float*)d_out;
    float* out_feats = out;                               // [n_rays, NF]
    float* out_depth = out + (size_t)n_rays * NF;         // [n_rays]
    float* out_ws    = out_depth + n_rays;                // [n_rays]
    float* out_alpha = out_ws + n_rays;                   // [n_rays]

    const int grid = (n_rays + 3) / 4;   // 1 ray per wave, 4 waves per block
    volren_kernel<<<grid, 256, 0, stream>>>(depths, sigma, feats, valid,
                                            out_feats, out_depth, out_ws,
                                            out_alpha, n_rays);
}

// Round 9
// 12.331 us; speedup vs baseline: 4.3300x; 1.4067x over previous
//
#include <hip/hip_runtime.h>

#define NS 128   // samples per ray
#define NF 32    // features

// One wave per ray, 2048 blocks x 4 waves, __launch_bounds__(256,3) so the HW
// dispatcher rebalances non-resident blocks (R7). New: early ray termination —
// the truncated-tail contribution is bounded by transmittance T_64 = exp(-tot_lo);
// if T_64 < 1e-4 (tot_lo > 9.21), samples [64,128) contribute < 5e-4 to any
// output (threshold 5.9e-2) and their 8 KB of feats are never read.
__global__ __launch_bounds__(256, 3)
void volren_kernel(const float* __restrict__ depths,   // [n_rays, NS]
                   const float* __restrict__ sigma,    // [n_rays, NS]
                   const float* __restrict__ feats,    // [n_rays, NS, NF]
                   const int*   __restrict__ valid,    // [n_rays]
                   float* __restrict__ out_feats,      // [n_rays, NF]
                   float* __restrict__ out_depth,      // [n_rays]
                   float* __restrict__ out_ws,         // [n_rays]
                   float* __restrict__ out_alpha,      // [n_rays]
                   int n_rays)
{
    const int lane = threadIdx.x & 63;
    const int ray  = blockIdx.x * 4 + (threadIdx.x >> 6);
    if (ray >= n_rays) return;

    const int j = lane >> 3;       // sample-sub index in [0,8)
    const int q = lane & 7;        // float4 quad index in [0,8)

    if (valid[ray] == 0) {
        // outputs are exactly zero; no input bytes needed
        if (j == 0)
            ((float4*)(out_feats + (size_t)ray * NF))[q] =
                make_float4(0.f, 0.f, 0.f, 0.f);
        if (lane == 0) {
            out_depth[ray] = 0.f;
            out_ws[ray]    = 0.f;
            out_alpha[ray] = 0.f;
        }
        return;
    }

    // ---------- issue scan inputs first (vmcnt retires in order) ----------
    const float* dp = depths + (size_t)ray * NS;
    const float* sp = sigma  + (size_t)ray * NS;
    float d_lo = dp[lane];
    float d_hi = dp[lane + 64];
    float s_lo = sp[lane];
    float s_hi = sp[lane + 64];

    // ---------- issue feats samples [0,64) unconditionally (scan overlaps flight) ----------
    const float4* fptr = (const float4*)(feats + (size_t)ray * NS * NF);
    float4 v0[8];
    #pragma unroll
    for (int it = 0; it < 8; ++it)
        v0[it] = fptr[(it * 8 + j) * 8 + q];

    // ---------- phase 1: free energy + wave-wide inclusive scan ----------
    float d_lo_nb = __shfl(d_lo, (lane + 1) & 63, 64);
    float d_hi_nb = __shfl(d_hi, (lane + 1) & 63, 64);
    float d64     = __shfl(d_hi, 0, 64);
    float d_lo_n  = (lane == 63) ? d64  : d_lo_nb;
    float d_hi_n  = (lane == 63) ? d_hi : d_hi_nb;   // last dist = 0

    float fe_lo = (d_lo_n - d_lo) * s_lo;
    float fe_hi = (d_hi_n - d_hi) * s_hi;

    float c_lo = fe_lo;
    #pragma unroll
    for (int off = 1; off < 64; off <<= 1) {
        float t = __shfl_up(c_lo, off, 64);
        if (lane >= off) c_lo += t;
    }
    float tot_lo = __shfl(c_lo, 63, 64);
    float c_hi = fe_hi;
    #pragma unroll
    for (int off = 1; off < 64; off <<= 1) {
        float t = __shfl_up(c_hi, off, 64);
        if (lane >= off) c_hi += t;
    }
    c_hi += tot_lo;

    // early-termination predicate: T_64 = exp(-tot_lo); tail weight sum <= T_64
    const bool need_hi = (tot_lo <= 9.2103404f);   // T_64 >= 1e-4

    // ---------- issue feats samples [64,128) only if they matter (~0.8% of rays) ----------
    float4 v1[8];
    if (need_hi) {
        #pragma unroll
        for (int it = 0; it < 8; ++it)
            v1[it] = fptr[((it + 8) * 8 + j) * 8 + q];
    }

    // w = alpha * exp(fe - cum) = exp(fe - cum) - exp(-cum)
    float w_lo = expf(fe_lo - c_lo) - expf(-c_lo);
    float w_hi = expf(fe_hi - c_hi) - expf(-c_hi);
    float a_lo = 1.0f - expf(-fe_lo);
    float a_hi = 1.0f - expf(-fe_hi);

    // scalar reductions: depth, alpha, weight-sum — exact (register-only, all 128)
    float dsum = w_lo * d_lo + w_hi * d_hi;
    float asum = w_lo * a_lo + w_hi * a_hi;
    float wsum = w_lo + w_hi;
    #pragma unroll
    for (int m = 1; m < 64; m <<= 1) {
        dsum += __shfl_xor(dsum, m, 64);
        asum += __shfl_xor(asum, m, 64);
        wsum += __shfl_xor(wsum, m, 64);
    }
    if (lane == 0) {
        out_depth[ray] = dsum;
        out_ws[ray]    = wsum;
        out_alpha[ray] = asum;
    }

    // ---------- phase 2: feats contraction (weights via in-wave shuffle) ----------
    float4 acc = make_float4(0.f, 0.f, 0.f, 0.f);
    #pragma unroll
    for (int it = 0; it < 8; ++it) {
        const float w = __shfl(w_lo, it * 8 + j, 64);
        acc.x += w * v0[it].x;
        acc.y += w * v0[it].y;
        acc.z += w * v0[it].z;
        acc.w += w * v0[it].w;
    }
    if (need_hi) {
        #pragma unroll
        for (int it = 0; it < 8; ++it) {
            const float w = __shfl(w_hi, it * 8 + j, 64);
            acc.x += w * v1[it].x;
            acc.y += w * v1[it].y;
            acc.z += w * v1[it].z;
            acc.w += w * v1[it].w;
        }
    }
    // reduce across the 8 sample-sub lanes (stride 8)
    #pragma unroll
    for (int m = 8; m < 64; m <<= 1) {
        acc.x += __shfl_xor(acc.x, m, 64);
        acc.y += __shfl_xor(acc.y, m, 64);
        acc.z += __shfl_xor(acc.z, m, 64);
        acc.w += __shfl_xor(acc.w, m, 64);
    }
    if (j == 0)
        ((float4*)(out_feats + (size_t)ray * NF))[q] = acc;
}

extern "C" void kernel_launch(void* const* d_in, const int* in_sizes, int n_in,
                              void* d_out, int out_size, void* d_ws, size_t ws_size,
                              hipStream_t stream) {
    const float* depths = (const float*)d_in[0];   // sampled_depths [B,R,S]
    const float* sigma  = (const float*)d_in[1];   // sigma          [B,R,S]
    const float* feats  = (const float*)d_in[2];   // feats          [B,R,S,F]
    // d_in[3] = max_depths (unused by the reference math)
    const int*   valid  = (const int*)d_in[4];     // valid_rays     [B,R]

    const int n_rays = in_sizes[4];                // B*R = 8192

    float* out       = (float*)d_out;
    float* out_feats = out;                               // [n_rays, NF]
    float* out_depth = out + (size_t)n_rays * NF;         // [n_rays]
    float* out_ws    = out_depth + n_rays;                // [n_rays]
    float* out_alpha = out_ws + n_rays;                   // [n_rays]

    const int grid = (n_rays + 3) / 4;   // 1 ray per wave, 4 waves per block
    volren_kernel<<<grid, 256, 0, stream>>>(depths, sigma, feats, valid,
                                            out_feats, out_depth, out_ws,
                                            out_alpha, n_rays);
}

// Round 10
// 11.058 us; speedup vs baseline: 4.8286x; 1.1151x over previous
//
#include <hip/hip_runtime.h>

#define NS 128   // samples per ray
#define NF 32    // features

// One wave per ray, 2048 blocks x 4 waves, __launch_bounds__(256,3) so the HW
// dispatcher rebalances non-resident blocks (R7). Early termination at
// 32-sample granularity: tail weight after sample s is bounded by
// T_s = exp(-cum_s); if T < 1e-4 the remaining feats are never read
// (error < ~1e-3 vs threshold 5.9e-2; validated in R8 at 64-granularity).
__global__ __launch_bounds__(256, 3)
void volren_kernel(const float* __restrict__ depths,   // [n_rays, NS]
                   const float* __restrict__ sigma,    // [n_rays, NS]
                   const float* __restrict__ feats,    // [n_rays, NS, NF]
                   const int*   __restrict__ valid,    // [n_rays]
                   float* __restrict__ out_feats,      // [n_rays, NF]
                   float* __restrict__ out_depth,      // [n_rays]
                   float* __restrict__ out_ws,         // [n_rays]
                   float* __restrict__ out_alpha,      // [n_rays]
                   int n_rays)
{
    const int lane = threadIdx.x & 63;
    const int ray  = blockIdx.x * 4 + (threadIdx.x >> 6);
    if (ray >= n_rays) return;

    const int j = lane >> 3;       // sample-sub index in [0,8)
    const int q = lane & 7;        // float4 quad index in [0,8)

    if (valid[ray] == 0) {
        // outputs are exactly zero; no input bytes needed
        if (j == 0)
            ((float4*)(out_feats + (size_t)ray * NF))[q] =
                make_float4(0.f, 0.f, 0.f, 0.f);
        if (lane == 0) {
            out_depth[ray] = 0.f;
            out_ws[ray]    = 0.f;
            out_alpha[ray] = 0.f;
        }
        return;
    }

    // ---------- issue scan inputs first (vmcnt retires in order) ----------
    const float* dp = depths + (size_t)ray * NS;
    const float* sp = sigma  + (size_t)ray * NS;
    float d_lo = dp[lane];
    float d_hi = dp[lane + 64];
    float s_lo = sp[lane];
    float s_hi = sp[lane + 64];

    // ---------- issue feats samples [0,32) unconditionally (scan overlaps flight) ----------
    const float4* fptr = (const float4*)(feats + (size_t)ray * NS * NF);
    float4 v0[4];
    #pragma unroll
    for (int it = 0; it < 4; ++it)
        v0[it] = fptr[(it * 8 + j) * 8 + q];

    // ---------- phase 1: free energy + wave-wide inclusive scan ----------
    float d_lo_nb = __shfl(d_lo, (lane + 1) & 63, 64);
    float d_hi_nb = __shfl(d_hi, (lane + 1) & 63, 64);
    float d64     = __shfl(d_hi, 0, 64);
    float d_lo_n  = (lane == 63) ? d64  : d_lo_nb;
    float d_hi_n  = (lane == 63) ? d_hi : d_hi_nb;   // last dist = 0

    float fe_lo = (d_lo_n - d_lo) * s_lo;
    float fe_hi = (d_hi_n - d_hi) * s_hi;

    float c_lo = fe_lo;
    #pragma unroll
    for (int off = 1; off < 64; off <<= 1) {
        float t = __shfl_up(c_lo, off, 64);
        if (lane >= off) c_lo += t;
    }
    float tot_lo = __shfl(c_lo, 63, 64);
    float cum_32 = __shfl(c_lo, 31, 64);
    float c_hi = fe_hi;
    #pragma unroll
    for (int off = 1; off < 64; off <<= 1) {
        float t = __shfl_up(c_hi, off, 64);
        if (lane >= off) c_hi += t;
    }
    c_hi += tot_lo;

    // termination predicates (T = exp(-cum) < 1e-4 -> tail negligible)
    const float TH = 9.2103404f;
    const bool need_b = (cum_32 <= TH);   // samples [32,64)   (~55% of rays)
    const bool need_c = (tot_lo <= TH);   // samples [64,128)  (~1% of rays)

    // ---------- conditional feats chunks ----------
    float4 v1[4];
    if (need_b) {
        #pragma unroll
        for (int it = 0; it < 4; ++it)
            v1[it] = fptr[((it + 4) * 8 + j) * 8 + q];
    }
    float4 v2[8];
    if (need_c) {
        #pragma unroll
        for (int it = 0; it < 8; ++it)
            v2[it] = fptr[((it + 8) * 8 + j) * 8 + q];
    }

    // w = alpha * exp(fe - cum) = exp(fe - cum) - exp(-cum)
    float w_lo = expf(fe_lo - c_lo) - expf(-c_lo);
    float w_hi = expf(fe_hi - c_hi) - expf(-c_hi);
    float a_lo = 1.0f - expf(-fe_lo);
    float a_hi = 1.0f - expf(-fe_hi);

    // scalar reductions: depth, alpha, weight-sum — exact (register-only, all 128)
    float dsum = w_lo * d_lo + w_hi * d_hi;
    float asum = w_lo * a_lo + w_hi * a_hi;
    float wsum = w_lo + w_hi;
    #pragma unroll
    for (int m = 1; m < 64; m <<= 1) {
        dsum += __shfl_xor(dsum, m, 64);
        asum += __shfl_xor(asum, m, 64);
        wsum += __shfl_xor(wsum, m, 64);
    }
    if (lane == 0) {
        out_depth[ray] = dsum;
        out_ws[ray]    = wsum;
        out_alpha[ray] = asum;
    }

    // ---------- phase 2: feats contraction (weights via in-wave shuffle) ----------
    float4 acc = make_float4(0.f, 0.f, 0.f, 0.f);
    #pragma unroll
    for (int it = 0; it < 4; ++it) {
        const float w = __shfl(w_lo, it * 8 + j, 64);
        acc.x += w * v0[it].x;
        acc.y += w * v0[it].y;
        acc.z += w * v0[it].z;
        acc.w += w * v0[it].w;
    }
    if (need_b) {
        #pragma unroll
        for (int it = 0; it < 4; ++it) {
            const float w = __shfl(w_lo, (it + 4) * 8 + j, 64);
            acc.x += w * v1[it].x;
            acc.y += w * v1[it].y;
            acc.z += w * v1[it].z;
            acc.w += w * v1[it].w;
        }
    }
    if (need_c) {
        #pragma unroll
        for (int it = 0; it < 8; ++it) {
            const float w = __shfl(w_hi, it * 8 + j, 64);
            acc.x += w * v2[it].x;
            acc.y += w * v2[it].y;
            acc.z += w * v2[it].z;
            acc.w += w * v2[it].w;
        }
    }
    // reduce across the 8 sample-sub lanes (stride 8)
    #pragma unroll
    for (int m = 8; m < 64; m <<= 1) {
        acc.x += __shfl_xor(acc.x, m, 64);
        acc.y += __shfl_xor(acc.y, m, 64);
        acc.z += __shfl_xor(acc.z, m, 64);
        acc.w += __shfl_xor(acc.w, m, 64);
    }
    if (j == 0)
        ((float4*)(out_feats + (size_t)ray * NF))[q] = acc;
}

extern "C" void kernel_launch(void* const* d_in, const int* in_sizes, int n_in,
                              void* d_out, int out_size, void* d_ws, size_t ws_size,
                              hipStream_t stream) {
    const float* depths = (const float*)d_in[0];   // sampled_depths [B,R,S]
    const float* sigma  = (const float*)d_in[1];   // sigma          [B,R,S]
    const float* feats  = (const float*)d_in[2];   // feats          [B,R,S,F]
    // d_in[3] = max_depths (unused by the reference math)
    const int*   valid  = (const int*)d_in[4];     // valid_rays     [B,R]

    const int n_rays = in_sizes[4];                // B*R = 8192

    float* out       = (float*)d_out;
    float* out_feats = out;                               // [n_rays, NF]
    float* out_depth = out + (size_t)n_rays * NF;         // [n_rays]
    float* out_ws    = out_depth + n_rays;                // [n_rays]
    float* out_alpha = out_ws + n_rays;                   // [n_rays]

    const int grid = (n_rays + 3) / 4;   // 1 ray per wave, 4 waves per block
    volren_kernel<<<grid, 256, 0, stream>>>(depths, sigma, feats, valid,
                                            out_feats, out_depth, out_ws,
                                            out_alpha, n_rays);
}